// Round 4
// baseline (583.572 us; speedup 1.0000x reference)
//
#include <hip/hip_runtime.h>
#include <hip/hip_bf16.h>

// Problem constants (fixed by harness setup_inputs).
#define S_LEN  2048
#define DMODEL 1024
#define NHEADS 16
#define DHEAD  64
#define TOKENS 4096   // B*S
#define QSCALE 0.04508422f   // (1/32) * log2(e): scores come out in log2 domain

typedef __attribute__((ext_vector_type(8))) short bf16x8;
typedef __attribute__((ext_vector_type(4))) float f32x4;

template <int M> struct IC { static constexpr int value = M; };

__device__ __forceinline__ float bf2f(unsigned short b) {
    union { unsigned u; float f; } v; v.u = ((unsigned)b) << 16;
    return v.f;
}
__device__ __forceinline__ unsigned cvt_pk_bf16(float lo, float hi) {
    unsigned r;
    asm("v_cvt_pk_bf16_f32 %0, %1, %2" : "=v"(r) : "v"(lo), "v"(hi));
    return r;
}
__device__ __forceinline__ unsigned short f2bf1(float x) {
    return (unsigned short)cvt_pk_bf16(x, x);
}
// wave-local LDS ordering fence (LDS in rel_attn is wave-private).
// sched_barrier(0) per rule-18: hipcc may hoist reg-only ops past asm waitcnt.
__device__ __forceinline__ void lds_fence() {
    asm volatile("s_waitcnt lgkmcnt(0)" ::: "memory");
    __builtin_amdgcn_sched_barrier(0);
}

// ---------------------------------------------------------------------------
// Kernel 1: fused 4-way projection GEMM.  out = X @ W^T + b  (bf16).
// z=0 (q): scaled by QSCALE, layout [BH][S][64]
// z=1 (k), z=3 (p): layout [BH][S][64]
// z=2 (v): layout [BH][64][S]  (transposed, packed b64 stores)
// ---------------------------------------------------------------------------
__global__ __launch_bounds__(256) void proj_gemm(
    const float* __restrict__ x0, const float* __restrict__ x1,
    const float* __restrict__ x2, const float* __restrict__ x3,
    const float* __restrict__ w0, const float* __restrict__ w1,
    const float* __restrict__ w2, const float* __restrict__ w3,
    const float* __restrict__ b0, const float* __restrict__ b1,
    const float* __restrict__ b2, const float* __restrict__ b3,
    unsigned short* __restrict__ o0, unsigned short* __restrict__ o1,
    unsigned short* __restrict__ o2, unsigned short* __restrict__ o3)
{
    const int z = blockIdx.z;
    const float* X  = (z == 0) ? x0 : (z == 1) ? x1 : (z == 2) ? x2 : x3;
    const float* W  = (z == 0) ? w0 : (z == 1) ? w1 : (z == 2) ? w2 : w3;
    const float* Bv = (z == 0) ? b0 : (z == 1) ? b1 : (z == 2) ? b2 : b3;
    unsigned short* O = (z == 0) ? o0 : (z == 1) ? o1 : (z == 2) ? o2 : o3;

    __shared__ __align__(16) unsigned short At[128 * 40];
    __shared__ __align__(16) unsigned short Bt[128 * 40];

    const int tid  = threadIdx.x;
    const int lane = tid & 63;
    const int w    = tid >> 6;
    const int wr   = w & 1, wc = w >> 1;
    const int m0   = blockIdx.x * 128;
    const int n0   = blockIdx.y * 128;
    const int l16  = lane & 15, lq = lane >> 4;

    f32x4 acc[4][4];
    #pragma unroll
    for (int i = 0; i < 4; i++)
        #pragma unroll
        for (int j = 0; j < 4; j++) acc[i][j] = (f32x4){0.f, 0.f, 0.f, 0.f};

    for (int k0 = 0; k0 < DMODEL; k0 += 32) {
        __syncthreads();
        #pragma unroll
        for (int i = 0; i < 4; i++) {
            int e = tid + i * 256;
            int row = e >> 3, cg = e & 7;
            float4 va = *(const float4*)&X[(long)(m0 + row) * DMODEL + k0 + cg * 4];
            uint2 ua; ua.x = cvt_pk_bf16(va.x, va.y); ua.y = cvt_pk_bf16(va.z, va.w);
            *(uint2*)&At[row * 40 + cg * 4] = ua;
            float4 vb = *(const float4*)&W[(long)(n0 + row) * DMODEL + k0 + cg * 4];
            uint2 ub; ub.x = cvt_pk_bf16(vb.x, vb.y); ub.y = cvt_pk_bf16(vb.z, vb.w);
            *(uint2*)&Bt[row * 40 + cg * 4] = ub;
        }
        __syncthreads();
        bf16x8 af[4], bfr[4];
        #pragma unroll
        for (int f = 0; f < 4; f++) {
            af[f]  = *(const bf16x8*)&At[(64 * wr + 16 * f + l16) * 40 + 8 * lq];
            bfr[f] = *(const bf16x8*)&Bt[(64 * wc + 16 * f + l16) * 40 + 8 * lq];
        }
        #pragma unroll
        for (int i = 0; i < 4; i++)
            #pragma unroll
            for (int j = 0; j < 4; j++)
                acc[i][j] = __builtin_amdgcn_mfma_f32_16x16x32_bf16(af[i], bfr[j], acc[i][j], 0, 0, 0);
    }

    #pragma unroll
    for (int j = 0; j < 4; j++) {
        int n_g = n0 + 64 * wc + 16 * j + l16;
        float bias = Bv[n_g];
        int h = n_g >> 6, dh = n_g & 63;
        if (z == 2) {
            // V^T layout [BH][64][S]: 4 consecutive m (=s) -> packed 8B store
            #pragma unroll
            for (int i = 0; i < 4; i++) {
                int m_g = m0 + 64 * wr + 16 * i + 4 * lq;
                int b = m_g >> 11, s = m_g & (S_LEN - 1);
                uint2 u;
                u.x = cvt_pk_bf16(acc[i][j][0] + bias, acc[i][j][1] + bias);
                u.y = cvt_pk_bf16(acc[i][j][2] + bias, acc[i][j][3] + bias);
                *(uint2*)&O[(long)(((b * NHEADS + h) * DHEAD) + dh) * S_LEN + s] = u;
            }
        } else {
            float scale = (z == 0) ? QSCALE : 1.0f;
            #pragma unroll
            for (int i = 0; i < 4; i++) {
                #pragma unroll
                for (int r = 0; r < 4; r++) {
                    int m_g = m0 + 64 * wr + 16 * i + 4 * lq + r;
                    int b = m_g >> 11, s = m_g & (S_LEN - 1);
                    O[(long)(((b * NHEADS + h) * S_LEN) + s) * DHEAD + dh] =
                        f2bf1((acc[i][j][r] + bias) * scale);
                }
            }
        }
    }
}

// ---------------------------------------------------------------------------
// Kernel 2: fused relative-position flash attention — barrier-free.
// 1D grid 1024 (XCD-swizzled -> (qt, bh)). 4 waves; wave w owns q-rows
// 16w..16w+15; operands read directly from global (L1/L2-resident).
// LDS is wave-private only: Tb (pos-shift roundtrip), Pb (P-pack for PV).
// Pos term for (q,c): Q[q + (c>q)] . P2[c-q+2047] where P2 is the plain p
// table with per-lane wrap (row m>=2049 -> m-2049); the m==2048 "zero row"
// is handled by select-discarding those score positions (c == q+1).
// MODE 0: c0<q0 (su=0) | MODE 1: c0>q0 (su=1) | MODE 2: c0==q0 (dual pass).
// ---------------------------------------------------------------------------
__global__ __launch_bounds__(256) void rel_attn(
    const unsigned short* __restrict__ Q,    // [BH][S][64] bf16, pre-scaled
    const unsigned short* __restrict__ K,    // [BH][S][64]
    const unsigned short* __restrict__ VT,   // [BH][64][S]
    const unsigned short* __restrict__ P,    // [BH][S][64] plain p table
    unsigned short* __restrict__ CTX)        // [B][S][H][64] bf16
{
    __shared__ __align__(16) unsigned short Tb[4 * 16 * 84];  // [w][qrow][t']
    __shared__ __align__(16) unsigned short Pb[4 * 16 * 72];  // [w][qrow][ci]

    const int tid  = threadIdx.x;
    const int lane = tid & 63;
    const int w    = tid >> 6;
    const int l16  = lane & 15;
    const int lq   = lane >> 4;

    const int wg = ((blockIdx.x & 7) << 7) + (blockIdx.x >> 3);  // XCD swizzle
    const int qt = wg & 31;
    const int bh = wg >> 5;
    const int q0 = qt << 6;
    const long baseQK = (long)bh * (S_LEN * DHEAD);
    const int qi_l = 16 * w + l16;

    // lane base pointers (tile adds c0*DHEAD / c0)
    const unsigned short* Kl  = K + baseQK + l16 * DHEAD + 8 * lq;
    const unsigned short* Vl  = VT + baseQK + (long)l16 * S_LEN + 8 * lq;
    const unsigned short* Pbh = P + baseQK;   // [2048][64]; row 2048 read lands in cx (discarded)

    // hoisted Q fragments: rows qi_l and qi_l+1
    bf16x8 qf0[2], qf1[2];
    {
        const unsigned short* qrow = Q + baseQK + (long)(q0 + qi_l) * DHEAD + 8 * lq;
        qf0[0] = *(const bf16x8*)(qrow);
        qf0[1] = *(const bf16x8*)(qrow + 32);
        qf1[0] = *(const bf16x8*)(qrow + DHEAD);
        qf1[1] = *(const bf16x8*)(qrow + DHEAD + 32);
    }

    float mrow = -1e30f, lrow = 0.f;
    f32x4 oacc[4];
    #pragma unroll
    for (int f = 0; f < 4; f++) oacc[f] = (f32x4){0.f, 0.f, 0.f, 0.f};

    unsigned short* tw        = &Tb[w * 1344 + l16 * 84 + 4 * lq];
    const unsigned short* tr  = &Tb[w * 1344 + l16 * 83 + 15 + 4 * lq];
    unsigned short* pw        = &Pb[w * 1152 + l16 * 72 + 4 * lq];
    const unsigned short* prd = &Pb[w * 1152 + l16 * 72 + 8 * lq];

    auto tile_body = [&](auto mc, int ct, bool dz) __attribute__((always_inline)) {
        constexpr int MODE = decltype(mc)::value;
        const int c0 = ct << 6;
        const unsigned short* Kp = Kl + c0 * DHEAD;
        const unsigned short* Vp = Vl + c0;
        const int mb = c0 - q0 + 2032 - 16 * w + l16;  // per-lane P2 window base

        // ---- content scores: cacc[fc][r] = S_c[ci=16fc+4lq+r][qi_l] ----
        f32x4 cacc[4];
        #pragma unroll
        for (int f = 0; f < 4; f++) cacc[f] = (f32x4){0.f, 0.f, 0.f, 0.f};
        #pragma unroll
        for (int fc = 0; fc < 4; ++fc)
            #pragma unroll
            for (int kk = 0; kk < 2; ++kk) {
                bf16x8 kf = *(const bf16x8*)(Kp + fc * (16 * DHEAD) + kk * 32);
                cacc[fc] = __builtin_amdgcn_mfma_f32_16x16x32_bf16(kf, qf0[kk], cacc[fc], 0, 0, 0);
            }

        // ---- pos tile pass A: per-wave 80-wide window, per-lane wrap ----
        f32x4 tacc[5];
        #pragma unroll
        for (int g = 0; g < 5; g++) tacc[g] = (f32x4){0.f, 0.f, 0.f, 0.f};
        #pragma unroll
        for (int cg = 0; cg < 5; ++cg) {
            int m = mb + 16 * cg;
            int pr = m - ((m >= 2049) ? 2049 : 0);
            const unsigned short* pp = Pbh + (long)pr * DHEAD + 8 * lq;
            bf16x8 pfa = *(const bf16x8*)(pp);
            bf16x8 pfb = *(const bf16x8*)(pp + 32);
            tacc[cg] = __builtin_amdgcn_mfma_f32_16x16x32_bf16(
                pfa, (MODE == 1) ? qf1[0] : qf0[0], tacc[cg], 0, 0, 0);
            tacc[cg] = __builtin_amdgcn_mfma_f32_16x16x32_bf16(
                pfb, (MODE == 1) ? qf1[1] : qf0[1], tacc[cg], 0, 0, 0);
        }
        lds_fence();   // prior-tile T/P LDS reads retired before overwrite
        #pragma unroll
        for (int cg = 0; cg < 5; ++cg) {
            uint2 u;
            u.x = cvt_pk_bf16(tacc[cg][0], tacc[cg][1]);
            u.y = cvt_pk_bf16(tacc[cg][2], tacc[cg][3]);
            *(uint2*)(tw + 16 * cg) = u;
        }
        lds_fence();   // T visible to all lanes of this wave

        // ---- score assembly ----
        float sc[4][4];
        if constexpr (MODE != 2) {
            #pragma unroll
            for (int fc = 0; fc < 4; ++fc)
                #pragma unroll
                for (int r = 0; r < 4; ++r)
                    sc[fc][r] = cacc[fc][r] + bf2f(tr[16 * fc + r]);
            if constexpr (MODE == 1) {
                // first super-diagonal tile: position (qi=63, ci=0) has
                // c == q+1 -> pos term is the shift zero (garbage in T).
                if (dz && qi_l == 63 && lq == 0) sc[0][0] = cacc[0][0];
            }
        } else {
            float v0[4][4];
            #pragma unroll
            for (int fc = 0; fc < 4; ++fc)
                #pragma unroll
                for (int r = 0; r < 4; ++r) v0[fc][r] = bf2f(tr[16 * fc + r]);
            lds_fence();   // v0 reads retired before pass-B overwrite
            // pass B: su=1 rows through the same buffer
            f32x4 tb2[5];
            #pragma unroll
            for (int g = 0; g < 5; g++) tb2[g] = (f32x4){0.f, 0.f, 0.f, 0.f};
            #pragma unroll
            for (int cg = 0; cg < 5; ++cg) {
                int m = mb + 16 * cg;
                int pr = m - ((m >= 2049) ? 2049 : 0);
                const unsigned short* pp = Pbh + (long)pr * DHEAD + 8 * lq;
                bf16x8 pfa = *(const bf16x8*)(pp);
                bf16x8 pfb = *(const bf16x8*)(pp + 32);
                tb2[cg] = __builtin_amdgcn_mfma_f32_16x16x32_bf16(pfa, qf1[0], tb2[cg], 0, 0, 0);
                tb2[cg] = __builtin_amdgcn_mfma_f32_16x16x32_bf16(pfb, qf1[1], tb2[cg], 0, 0, 0);
            }
            #pragma unroll
            for (int cg = 0; cg < 5; ++cg) {
                uint2 u;
                u.x = cvt_pk_bf16(tb2[cg][0], tb2[cg][1]);
                u.y = cvt_pk_bf16(tb2[cg][2], tb2[cg][3]);
                *(uint2*)(tw + 16 * cg) = u;
            }
            lds_fence();
            #pragma unroll
            for (int fc = 0; fc < 4; ++fc)
                #pragma unroll
                for (int r = 0; r < 4; ++r) {
                    float v1 = bf2f(tr[16 * fc + r]);
                    int ci = 16 * fc + 4 * lq + r;
                    // c==q+1 -> zero pos term (discards the garbage column)
                    float term = (ci == qi_l + 1) ? 0.f
                               : ((ci > qi_l) ? v1 : v0[fc][r]);
                    sc[fc][r] = cacc[fc][r] + term;
                }
        }

        // ---- online softmax (log2 domain; lane owns row qi_l) ----
        float tmax = sc[0][0];
        #pragma unroll
        for (int fc = 0; fc < 4; ++fc)
            #pragma unroll
            for (int r = 0; r < 4; ++r) tmax = fmaxf(tmax, sc[fc][r]);
        tmax = fmaxf(tmax, __shfl_xor(tmax, 16, 64));
        tmax = fmaxf(tmax, __shfl_xor(tmax, 32, 64));
        float nm = fmaxf(mrow, tmax);
        float alpha = exp2f(mrow - nm);
        mrow = nm;
        float pv[4][4];
        float rs = 0.f;
        #pragma unroll
        for (int fc = 0; fc < 4; ++fc)
            #pragma unroll
            for (int r = 0; r < 4; ++r) {
                float p = exp2f(sc[fc][r] - nm);
                pv[fc][r] = p;
                rs += p;
            }
        rs += __shfl_xor(rs, 16, 64);
        rs += __shfl_xor(rs, 32, 64);
        lrow = lrow * alpha + rs;
        #pragma unroll
        for (int f = 0; f < 4; f++)
            #pragma unroll
            for (int r = 0; r < 4; r++) oacc[f][r] *= alpha;

        // ---- pack P into Pb, read back as PV B-fragments ----
        #pragma unroll
        for (int fc = 0; fc < 4; ++fc) {
            uint2 u;
            u.x = cvt_pk_bf16(pv[fc][0], pv[fc][1]);
            u.y = cvt_pk_bf16(pv[fc][2], pv[fc][3]);
            *(uint2*)(pw + 16 * fc) = u;
        }
        lds_fence();
        bf16x8 pfr[2];
        pfr[0] = *(const bf16x8*)(prd);
        pfr[1] = *(const bf16x8*)(prd + 32);

        // ---- PV: oacc[fa][r] = O[qi_l][dh=16fa+4lq+r] ----
        #pragma unroll
        for (int kk = 0; kk < 2; ++kk)
            #pragma unroll
            for (int fa = 0; fa < 4; ++fa) {
                bf16x8 vf = *(const bf16x8*)(Vp + fa * (16 * S_LEN) + kk * 32);
                oacc[fa] = __builtin_amdgcn_mfma_f32_16x16x32_bf16(vf, pfr[kk], oacc[fa], 0, 0, 0);
            }
    };

    for (int ct = 0; ct < qt; ++ct) tile_body(IC<0>{}, ct, false);
    tile_body(IC<2>{}, qt, false);
    if (qt < 31) {
        tile_body(IC<1>{}, qt + 1, true);
        for (int ct = qt + 2; ct < S_LEN / 64; ++ct) tile_body(IC<1>{}, ct, false);
    }

    // epilogue: lane owns row q0+qi_l; 4 consecutive dh -> packed 8B stores
    const int b = bh >> 4, h = bh & 15;
    const float rinv = 1.0f / lrow;
    unsigned short* op = CTX + ((long)(b * S_LEN + q0 + qi_l) * NHEADS + h) * DHEAD + 4 * lq;
    #pragma unroll
    for (int fa = 0; fa < 4; ++fa) {
        uint2 u;
        u.x = cvt_pk_bf16(oacc[fa][0] * rinv, oacc[fa][1] * rinv);
        u.y = cvt_pk_bf16(oacc[fa][2] * rinv, oacc[fa][3] * rinv);
        *(uint2*)(op + 16 * fa) = u;
    }
}

// ---------------------------------------------------------------------------
// Kernel 3: output GEMM.  out = ctx(bf16) @ Wo^T + bo, fp32 out.
// ---------------------------------------------------------------------------
__global__ __launch_bounds__(256) void out_gemm(
    const unsigned short* __restrict__ A,  // ctx bf16 [4096][1024]
    const float* __restrict__ W,           // Wo [1024][1024]
    const float* __restrict__ Bv,          // bo
    float* __restrict__ O)                 // [4096][1024] fp32
{
    __shared__ __align__(16) unsigned short At[128 * 40];
    __shared__ __align__(16) unsigned short Bt[128 * 40];

    const int tid  = threadIdx.x;
    const int lane = tid & 63;
    const int w    = tid >> 6;
    const int wr   = w & 1, wc = w >> 1;
    const int m0   = blockIdx.x * 128;
    const int n0   = blockIdx.y * 128;
    const int l16  = lane & 15, lq = lane >> 4;

    f32x4 acc[4][4];
    #pragma unroll
    for (int i = 0; i < 4; i++)
        #pragma unroll
        for (int j = 0; j < 4; j++) acc[i][j] = (f32x4){0.f, 0.f, 0.f, 0.f};

    for (int k0 = 0; k0 < DMODEL; k0 += 32) {
        __syncthreads();
        #pragma unroll
        for (int i = 0; i < 2; i++) {
            int e = tid + i * 256;
            int row = e >> 2, sg = e & 3;
            *(float4*)&At[row * 40 + sg * 8] =
                *(const float4*)&A[(long)(m0 + row) * DMODEL + k0 + sg * 8];
        }
        #pragma unroll
        for (int i = 0; i < 4; i++) {
            int e = tid + i * 256;
            int row = e >> 3, cg = e & 7;
            float4 vb = *(const float4*)&W[(long)(n0 + row) * DMODEL + k0 + cg * 4];
            uint2 ub; ub.x = cvt_pk_bf16(vb.x, vb.y); ub.y = cvt_pk_bf16(vb.z, vb.w);
            *(uint2*)&Bt[row * 40 + cg * 4] = ub;
        }
        __syncthreads();
        bf16x8 af[4], bfr[4];
        #pragma unroll
        for (int f = 0; f < 4; f++) {
            af[f]  = *(const bf16x8*)&At[(64 * wr + 16 * f + l16) * 40 + 8 * lq];
            bfr[f] = *(const bf16x8*)&Bt[(64 * wc + 16 * f + l16) * 40 + 8 * lq];
        }
        #pragma unroll
        for (int i = 0; i < 4; i++)
            #pragma unroll
            for (int j = 0; j < 4; j++)
                acc[i][j] = __builtin_amdgcn_mfma_f32_16x16x32_bf16(af[i], bfr[j], acc[i][j], 0, 0, 0);
    }

    #pragma unroll
    for (int j = 0; j < 4; j++) {
        int n_g = n0 + 64 * wc + 16 * j + l16;
        float bias = Bv[n_g];
        #pragma unroll
        for (int i = 0; i < 4; i++) {
            #pragma unroll
            for (int r = 0; r < 4; r++) {
                int m_g = m0 + 64 * wr + 16 * i + 4 * lq + r;
                O[(long)m_g * DMODEL + n_g] = acc[i][j][r] + bias;
            }
        }
    }
}

// ---------------------------------------------------------------------------
extern "C" void kernel_launch(void* const* d_in, const int* in_sizes, int n_in,
                              void* d_out, int out_size, void* d_ws, size_t ws_size,
                              hipStream_t stream) {
    (void)in_sizes; (void)n_in; (void)out_size; (void)ws_size;
    const float* query = (const float*)d_in[0];
    const float* key_  = (const float*)d_in[1];
    const float* value = (const float*)d_in[2];
    const float* pos   = (const float*)d_in[3];
    const float* Wq = (const float*)d_in[4];  const float* bq = (const float*)d_in[5];
    const float* Wk = (const float*)d_in[6];  const float* bk = (const float*)d_in[7];
    const float* Wv = (const float*)d_in[8];  const float* bv = (const float*)d_in[9];
    const float* Wp = (const float*)d_in[10]; const float* bp = (const float*)d_in[11];
    const float* Wo = (const float*)d_in[12]; const float* bo = (const float*)d_in[13];
    float* out = (float*)d_out;

    const long NE = (long)TOKENS * DMODEL;   // 4,194,304 elements per tensor
    unsigned short* qb = (unsigned short*)d_ws;
    unsigned short* kb = qb + NE;
    unsigned short* vb = kb + NE;            // V^T layout [BH][64][S]
    unsigned short* pb = vb + NE;            // plain p table [BH][S][64]
    unsigned short* cx = pb + NE;            // total ws use: 5 * 8 MB = 40 MB

    proj_gemm<<<dim3(32, 8, 4), 256, 0, stream>>>(
        query, key_, value, pos, Wq, Wk, Wv, Wp, bq, bk, bv, bp, qb, kb, vb, pb);
    rel_attn<<<1024, 256, 0, stream>>>(qb, kb, vb, pb, cx);
    out_gemm<<<dim3(32, 8), 256, 0, stream>>>(cx, Wo, bo, out);
}

// Round 5
// 269.211 us; speedup vs baseline: 2.1677x; 2.1677x over previous
//
#include <hip/hip_runtime.h>
#include <hip/hip_bf16.h>

// Problem constants (fixed by harness setup_inputs).
#define S_LEN  2048
#define DMODEL 1024
#define NHEADS 16
#define DHEAD  64
#define TOKENS 4096   // B*S
#define QSCALE 0.04508422f   // (1/32) * log2(e): scores come out in log2 domain

typedef __attribute__((ext_vector_type(8))) short bf16x8;
typedef __attribute__((ext_vector_type(4))) float f32x4;

template <int M> struct IC { static constexpr int value = M; };

__device__ __forceinline__ float bf2f(unsigned short b) {
    union { unsigned u; float f; } v; v.u = ((unsigned)b) << 16;
    return v.f;
}
__device__ __forceinline__ unsigned cvt_pk_bf16(float lo, float hi) {
    unsigned r;
    asm("v_cvt_pk_bf16_f32 %0, %1, %2" : "=v"(r) : "v"(lo), "v"(hi));
    return r;
}
__device__ __forceinline__ unsigned short f2bf1(float x) {
    return (unsigned short)cvt_pk_bf16(x, x);
}
// wave-local LDS ordering fence (guards wave-private Tb/Pb roundtrips).
__device__ __forceinline__ void lds_fence() {
    asm volatile("s_waitcnt lgkmcnt(0)" ::: "memory");
    __builtin_amdgcn_sched_barrier(0);
}
// global -> LDS DMA, 16B per lane. LDS dest = wave-uniform base + lane*16;
// global src is per-lane (enables source-side swizzle).
__device__ __forceinline__ void gload_lds16(const void* g, void* l) {
    __builtin_amdgcn_global_load_lds(
        (const __attribute__((address_space(1))) void*)g,
        (__attribute__((address_space(3))) void*)l, 16, 0, 0);
}

// ---------------------------------------------------------------------------
// Kernel 1: fused 4-way projection GEMM.  out = X @ W^T + b  (bf16).
// z=0 (q): scaled by QSCALE, layout [BH][S][64]
// z=1 (k), z=3 (p): layout [BH][S][64]
// z=2 (v): layout [BH][64][S]  (transposed, packed b64 stores)
// ---------------------------------------------------------------------------
__global__ __launch_bounds__(256) void proj_gemm(
    const float* __restrict__ x0, const float* __restrict__ x1,
    const float* __restrict__ x2, const float* __restrict__ x3,
    const float* __restrict__ w0, const float* __restrict__ w1,
    const float* __restrict__ w2, const float* __restrict__ w3,
    const float* __restrict__ b0, const float* __restrict__ b1,
    const float* __restrict__ b2, const float* __restrict__ b3,
    unsigned short* __restrict__ o0, unsigned short* __restrict__ o1,
    unsigned short* __restrict__ o2, unsigned short* __restrict__ o3)
{
    const int z = blockIdx.z;
    const float* X  = (z == 0) ? x0 : (z == 1) ? x1 : (z == 2) ? x2 : x3;
    const float* W  = (z == 0) ? w0 : (z == 1) ? w1 : (z == 2) ? w2 : w3;
    const float* Bv = (z == 0) ? b0 : (z == 1) ? b1 : (z == 2) ? b2 : b3;
    unsigned short* O = (z == 0) ? o0 : (z == 1) ? o1 : (z == 2) ? o2 : o3;

    __shared__ __align__(16) unsigned short At[128 * 40];
    __shared__ __align__(16) unsigned short Bt[128 * 40];

    const int tid  = threadIdx.x;
    const int lane = tid & 63;
    const int w    = tid >> 6;
    const int wr   = w & 1, wc = w >> 1;
    const int m0   = blockIdx.x * 128;
    const int n0   = blockIdx.y * 128;
    const int l16  = lane & 15, lq = lane >> 4;

    f32x4 acc[4][4];
    #pragma unroll
    for (int i = 0; i < 4; i++)
        #pragma unroll
        for (int j = 0; j < 4; j++) acc[i][j] = (f32x4){0.f, 0.f, 0.f, 0.f};

    for (int k0 = 0; k0 < DMODEL; k0 += 32) {
        __syncthreads();
        #pragma unroll
        for (int i = 0; i < 4; i++) {
            int e = tid + i * 256;
            int row = e >> 3, cg = e & 7;
            float4 va = *(const float4*)&X[(long)(m0 + row) * DMODEL + k0 + cg * 4];
            uint2 ua; ua.x = cvt_pk_bf16(va.x, va.y); ua.y = cvt_pk_bf16(va.z, va.w);
            *(uint2*)&At[row * 40 + cg * 4] = ua;
            float4 vb = *(const float4*)&W[(long)(n0 + row) * DMODEL + k0 + cg * 4];
            uint2 ub; ub.x = cvt_pk_bf16(vb.x, vb.y); ub.y = cvt_pk_bf16(vb.z, vb.w);
            *(uint2*)&Bt[row * 40 + cg * 4] = ub;
        }
        __syncthreads();
        bf16x8 af[4], bfr[4];
        #pragma unroll
        for (int f = 0; f < 4; f++) {
            af[f]  = *(const bf16x8*)&At[(64 * wr + 16 * f + l16) * 40 + 8 * lq];
            bfr[f] = *(const bf16x8*)&Bt[(64 * wc + 16 * f + l16) * 40 + 8 * lq];
        }
        #pragma unroll
        for (int i = 0; i < 4; i++)
            #pragma unroll
            for (int j = 0; j < 4; j++)
                acc[i][j] = __builtin_amdgcn_mfma_f32_16x16x32_bf16(af[i], bfr[j], acc[i][j], 0, 0, 0);
    }

    #pragma unroll
    for (int j = 0; j < 4; j++) {
        int n_g = n0 + 64 * wc + 16 * j + l16;
        float bias = Bv[n_g];
        int h = n_g >> 6, dh = n_g & 63;
        if (z == 2) {
            #pragma unroll
            for (int i = 0; i < 4; i++) {
                int m_g = m0 + 64 * wr + 16 * i + 4 * lq;
                int b = m_g >> 11, s = m_g & (S_LEN - 1);
                uint2 u;
                u.x = cvt_pk_bf16(acc[i][j][0] + bias, acc[i][j][1] + bias);
                u.y = cvt_pk_bf16(acc[i][j][2] + bias, acc[i][j][3] + bias);
                *(uint2*)&O[(long)(((b * NHEADS + h) * DHEAD) + dh) * S_LEN + s] = u;
            }
        } else {
            float scale = (z == 0) ? QSCALE : 1.0f;
            #pragma unroll
            for (int i = 0; i < 4; i++) {
                #pragma unroll
                for (int r = 0; r < 4; r++) {
                    int m_g = m0 + 64 * wr + 16 * i + 4 * lq + r;
                    int b = m_g >> 11, s = m_g & (S_LEN - 1);
                    O[(long)(((b * NHEADS + h) * S_LEN) + s) * DHEAD + dh] =
                        f2bf1((acc[i][j][r] + bias) * scale);
                }
            }
        }
    }
}

// ---------------------------------------------------------------------------
// Kernel 2: fused relative-position flash attention.
// Bulk-staged via global_load_lds (XOR-granule-swizzled source, linear LDS),
// P2 window as a 128-row ring (stage 64 new rows/tile), V direct-to-VGPR,
// 2 barriers/tile, wave-private Tb/Pb aliased region for the shift/PV packs.
// MODE 0: c0<q0 | MODE 1: c0>q0 | MODE 2: c0==q0 (dual pos pass).
// ---------------------------------------------------------------------------
__global__ __launch_bounds__(256, 3) void rel_attn(
    const unsigned short* __restrict__ Q,    // [BH][S][64] bf16, pre-scaled
    const unsigned short* __restrict__ K,    // [BH][S][64]
    const unsigned short* __restrict__ VT,   // [BH][64][S]
    const unsigned short* __restrict__ P,    // [BH][S][64] plain p table
    unsigned short* __restrict__ CTX)        // [B][S][H][64] bf16
{
    __shared__ __align__(16) unsigned short Kb[64 * 64];     // 8 KB, swizzled granules
    __shared__ __align__(16) unsigned short P2b[128 * 64];   // 16 KB ring, swizzled
    __shared__ __align__(16) unsigned short WPb[4 * 1344];   // per-wave T(16x84)/P(16x72) alias

    const int tid  = threadIdx.x;
    const int lane = tid & 63;
    const int w    = tid >> 6;
    const int l16  = lane & 15;
    const int lq   = lane >> 4;

    const int wg = ((blockIdx.x & 7) << 7) + (blockIdx.x >> 3);  // XCD swizzle
    const int qt = wg & 31;
    const int bh = wg >> 5;
    const int q0 = qt << 6;
    const long baseQK = (long)bh * (S_LEN * DHEAD);
    const int qi_l = 16 * w + l16;

    const unsigned short* Kbh = K + baseQK;
    const unsigned short* Pbh = P + baseQK;
    const unsigned short* Vl  = VT + baseQK + (long)l16 * S_LEN + 8 * lq;

    // swizzled granule offsets for fragment reads (shorts); row&7 == l16&7
    const int gx0 = ((0 + lq) ^ (l16 & 7)) * 8;
    const int gx1 = ((4 + lq) ^ (l16 & 7)) * 8;

    // hoisted Q fragments: rows qi_l and qi_l+1
    bf16x8 qf0[2], qf1[2];
    {
        const unsigned short* qrow = Q + baseQK + (long)(q0 + qi_l) * DHEAD + 8 * lq;
        qf0[0] = *(const bf16x8*)(qrow);
        qf0[1] = *(const bf16x8*)(qrow + 32);
        qf1[0] = *(const bf16x8*)(qrow + DHEAD);
        qf1[1] = *(const bf16x8*)(qrow + DHEAD + 32);
    }

    // staging: global_load_lds, source pre-swizzled (g = gs ^ (row&7))
    const int srow = lane >> 3;            // stage row-within-8 AND row&7
    const int sgr  = (lane & 7) ^ srow;    // source granule for this lane
    auto stage_K = [&](int kr0) {          // K rows [kr0, kr0+64)
        #pragma unroll
        for (int j = 0; j < 2; ++j) {
            int idx = w * 2 + j;
            const unsigned short* src = Kbh + (long)(kr0 + idx * 8 + srow) * 64 + sgr * 8;
            gload_lds16(src, &Kb[idx * 512]);
        }
    };
    auto stage_P2 = [&](int mfirst) {      // 64 window rows [mfirst, mfirst+64), mfirst%64==0
        #pragma unroll
        for (int j = 0; j < 2; ++j) {
            int idx = w * 2 + j;
            int m = mfirst + idx * 8 + srow;
            int pr = m - ((m >= 2049) ? 2049 : 0);   // wrap; m==2048 garbage discarded later
            const unsigned short* src = Pbh + (long)pr * 64 + sgr * 8;
            gload_lds16(src, &P2b[((mfirst + idx * 8) & 127) * 64]);
        }
    };

    float mrow = -1e30f, lrow = 0.f;
    f32x4 oacc[4];
    #pragma unroll
    for (int f = 0; f < 4; f++) oacc[f] = (f32x4){0.f, 0.f, 0.f, 0.f};

    unsigned short* tw        = &WPb[w * 1344 + l16 * 84 + 4 * lq];
    const unsigned short* tr  = &WPb[w * 1344 + l16 * 83 + 15 + 4 * lq];
    unsigned short* pw        = &WPb[w * 1344 + l16 * 72 + 4 * lq];
    const unsigned short* prd = &WPb[w * 1344 + l16 * 72 + 8 * lq];

    // prologue: stage K tile 0 + full 128-row P2 window for tile 0
    stage_K(0);
    {
        const int W0 = 1984 - q0;
        #pragma unroll
        for (int j = 0; j < 4; ++j) {
            int idx = w * 4 + j;
            int m = W0 + idx * 8 + srow;
            int pr = m - ((m >= 2049) ? 2049 : 0);
            const unsigned short* src = Pbh + (long)pr * 64 + sgr * 8;
            gload_lds16(src, &P2b[((W0 + idx * 8) & 127) * 64]);
        }
    }
    __syncthreads();

    auto tile_body = [&](auto mc, int ct, bool dz) __attribute__((always_inline)) {
        constexpr int MODE = decltype(mc)::value;
        const int c0 = ct << 6;
        const int mb = c0 - q0 + 2032 - 16 * w + l16;   // per-lane pos window row, cg=0

        // ---- content scores from Kb (swizzled, conflict-free) ----
        f32x4 cacc[4];
        #pragma unroll
        for (int f = 0; f < 4; f++) cacc[f] = (f32x4){0.f, 0.f, 0.f, 0.f};
        #pragma unroll
        for (int fc = 0; fc < 4; ++fc) {
            bf16x8 k0v = *(const bf16x8*)&Kb[(16 * fc + l16) * 64 + gx0];
            bf16x8 k1v = *(const bf16x8*)&Kb[(16 * fc + l16) * 64 + gx1];
            cacc[fc] = __builtin_amdgcn_mfma_f32_16x16x32_bf16(k0v, qf0[0], cacc[fc], 0, 0, 0);
            cacc[fc] = __builtin_amdgcn_mfma_f32_16x16x32_bf16(k1v, qf0[1], cacc[fc], 0, 0, 0);
        }

        // ---- pos pass A from P2 ring ----
        f32x4 tacc[5];
        #pragma unroll
        for (int g = 0; g < 5; g++) tacc[g] = (f32x4){0.f, 0.f, 0.f, 0.f};
        #pragma unroll
        for (int cg = 0; cg < 5; ++cg) {
            int sb = ((mb + 16 * cg) & 127) * 64;
            bf16x8 p0 = *(const bf16x8*)&P2b[sb + gx0];
            bf16x8 p1 = *(const bf16x8*)&P2b[sb + gx1];
            tacc[cg] = __builtin_amdgcn_mfma_f32_16x16x32_bf16(
                p0, (MODE == 1) ? qf1[0] : qf0[0], tacc[cg], 0, 0, 0);
            tacc[cg] = __builtin_amdgcn_mfma_f32_16x16x32_bf16(
                p1, (MODE == 1) ? qf1[1] : qf0[1], tacc[cg], 0, 0, 0);
        }

        __syncthreads();   // all waves done reading Kb / P2 ring (pass A)

        if constexpr (MODE != 2) {
            if (ct < 31) { stage_K(c0 + 64); stage_P2(c0 - q0 + 2112); }
        }

        // ---- V fragments direct global -> VGPR (consumed at PV) ----
        bf16x8 vf[2][4];
        #pragma unroll
        for (int kk = 0; kk < 2; ++kk)
            #pragma unroll
            for (int fa = 0; fa < 4; ++fa)
                vf[kk][fa] = *(const bf16x8*)(Vl + c0 + fa * (16 * S_LEN) + kk * 32);

        // ---- T roundtrip (wave-private; WAR vs prior Pb reads -> fence) ----
        lds_fence();
        #pragma unroll
        for (int cg = 0; cg < 5; ++cg) {
            uint2 u;
            u.x = cvt_pk_bf16(tacc[cg][0], tacc[cg][1]);
            u.y = cvt_pk_bf16(tacc[cg][2], tacc[cg][3]);
            *(uint2*)(tw + 16 * cg) = u;
        }
        lds_fence();

        float sc[4][4];
        if constexpr (MODE != 2) {
            #pragma unroll
            for (int fc = 0; fc < 4; ++fc)
                #pragma unroll
                for (int r = 0; r < 4; ++r)
                    sc[fc][r] = cacc[fc][r] + bf2f(tr[16 * fc + r]);
            if constexpr (MODE == 1) {
                // first super-diagonal tile: (qi=63, ci=0) has c==q+1 -> zero pos term
                if (dz && qi_l == 63 && lq == 0) sc[0][0] = cacc[0][0];
            }
        } else {
            float v0[4][4];
            #pragma unroll
            for (int fc = 0; fc < 4; ++fc)
                #pragma unroll
                for (int r = 0; r < 4; ++r) v0[fc][r] = bf2f(tr[16 * fc + r]);
            lds_fence();
            // pass B (su=1) reads the ring again -> ring not yet overwritten
            f32x4 tb2[5];
            #pragma unroll
            for (int g = 0; g < 5; g++) tb2[g] = (f32x4){0.f, 0.f, 0.f, 0.f};
            #pragma unroll
            for (int cg = 0; cg < 5; ++cg) {
                int sb = ((mb + 16 * cg) & 127) * 64;
                bf16x8 p0 = *(const bf16x8*)&P2b[sb + gx0];
                bf16x8 p1 = *(const bf16x8*)&P2b[sb + gx1];
                tb2[cg] = __builtin_amdgcn_mfma_f32_16x16x32_bf16(p0, qf1[0], tb2[cg], 0, 0, 0);
                tb2[cg] = __builtin_amdgcn_mfma_f32_16x16x32_bf16(p1, qf1[1], tb2[cg], 0, 0, 0);
            }
            __syncthreads();   // all waves done pass-B ring reads
            if (ct < 31) { stage_K(c0 + 64); stage_P2(c0 - q0 + 2112); }
            #pragma unroll
            for (int cg = 0; cg < 5; ++cg) {
                uint2 u;
                u.x = cvt_pk_bf16(tb2[cg][0], tb2[cg][1]);
                u.y = cvt_pk_bf16(tb2[cg][2], tb2[cg][3]);
                *(uint2*)(tw + 16 * cg) = u;
            }
            lds_fence();
            #pragma unroll
            for (int fc = 0; fc < 4; ++fc)
                #pragma unroll
                for (int r = 0; r < 4; ++r) {
                    float v1 = bf2f(tr[16 * fc + r]);
                    int ci = 16 * fc + 4 * lq + r;
                    float term = (ci == qi_l + 1) ? 0.f
                               : ((ci > qi_l) ? v1 : v0[fc][r]);
                    sc[fc][r] = cacc[fc][r] + term;
                }
        }

        // ---- online softmax (log2 domain; lane owns row qi_l) ----
        float tmax = sc[0][0];
        #pragma unroll
        for (int fc = 0; fc < 4; ++fc)
            #pragma unroll
            for (int r = 0; r < 4; ++r) tmax = fmaxf(tmax, sc[fc][r]);
        tmax = fmaxf(tmax, __shfl_xor(tmax, 16, 64));
        tmax = fmaxf(tmax, __shfl_xor(tmax, 32, 64));
        float nm = fmaxf(mrow, tmax);
        float alpha = __builtin_amdgcn_exp2f(mrow - nm);
        mrow = nm;
        float pv[4][4];
        float rs = 0.f;
        #pragma unroll
        for (int fc = 0; fc < 4; ++fc)
            #pragma unroll
            for (int r = 0; r < 4; ++r) {
                float p = __builtin_amdgcn_exp2f(sc[fc][r] - nm);
                pv[fc][r] = p;
                rs += p;
            }
        rs += __shfl_xor(rs, 16, 64);
        rs += __shfl_xor(rs, 32, 64);
        lrow = lrow * alpha + rs;
        #pragma unroll
        for (int f = 0; f < 4; f++)
            #pragma unroll
            for (int r = 0; r < 4; r++) oacc[f][r] *= alpha;

        // ---- Pb pack (aliases T region; T reads retired -> fence) ----
        lds_fence();
        #pragma unroll
        for (int fc = 0; fc < 4; ++fc) {
            uint2 u;
            u.x = cvt_pk_bf16(pv[fc][0], pv[fc][1]);
            u.y = cvt_pk_bf16(pv[fc][2], pv[fc][3]);
            *(uint2*)(pw + 16 * fc) = u;
        }
        lds_fence();
        bf16x8 pfr[2];
        pfr[0] = *(const bf16x8*)(prd);
        pfr[1] = *(const bf16x8*)(prd + 32);

        // ---- PV ----
        #pragma unroll
        for (int kk = 0; kk < 2; ++kk)
            #pragma unroll
            for (int fa = 0; fa < 4; ++fa)
                oacc[fa] = __builtin_amdgcn_mfma_f32_16x16x32_bf16(vf[kk][fa], pfr[kk], oacc[fa], 0, 0, 0);

        __syncthreads();   // staged K/P2 landed; all waves ready for next tile
    };

    for (int ct = 0; ct < qt; ++ct) tile_body(IC<0>{}, ct, false);
    tile_body(IC<2>{}, qt, false);
    if (qt < 31) {
        tile_body(IC<1>{}, qt + 1, true);
        for (int ct = qt + 2; ct < S_LEN / 64; ++ct) tile_body(IC<1>{}, ct, false);
    }

    // epilogue
    const int b = bh >> 4, h = bh & 15;
    const float rinv = 1.0f / lrow;
    unsigned short* op = CTX + ((long)(b * S_LEN + q0 + qi_l) * NHEADS + h) * DHEAD + 4 * lq;
    #pragma unroll
    for (int fa = 0; fa < 4; ++fa) {
        uint2 u;
        u.x = cvt_pk_bf16(oacc[fa][0] * rinv, oacc[fa][1] * rinv);
        u.y = cvt_pk_bf16(oacc[fa][2] * rinv, oacc[fa][3] * rinv);
        *(uint2*)(op + 16 * fa) = u;
    }
}

// ---------------------------------------------------------------------------
// Kernel 3: output GEMM.  out = ctx(bf16) @ Wo^T + bo, fp32 out.
// ---------------------------------------------------------------------------
__global__ __launch_bounds__(256) void out_gemm(
    const unsigned short* __restrict__ A,
    const float* __restrict__ W,
    const float* __restrict__ Bv,
    float* __restrict__ O)
{
    __shared__ __align__(16) unsigned short At[128 * 40];
    __shared__ __align__(16) unsigned short Bt[128 * 40];

    const int tid  = threadIdx.x;
    const int lane = tid & 63;
    const int w    = tid >> 6;
    const int wr   = w & 1, wc = w >> 1;
    const int m0   = blockIdx.x * 128;
    const int n0   = blockIdx.y * 128;
    const int l16  = lane & 15, lq = lane >> 4;

    f32x4 acc[4][4];
    #pragma unroll
    for (int i = 0; i < 4; i++)
        #pragma unroll
        for (int j = 0; j < 4; j++) acc[i][j] = (f32x4){0.f, 0.f, 0.f, 0.f};

    for (int k0 = 0; k0 < DMODEL; k0 += 32) {
        __syncthreads();
        #pragma unroll
        for (int i = 0; i < 2; i++) {
            int e = tid + i * 256;
            int row = e >> 2, sg = e & 3;
            *(float4*)&At[row * 40 + sg * 8] =
                *(const float4*)&A[(long)(m0 + row) * DMODEL + k0 + sg * 8];
        }
        #pragma unroll
        for (int i = 0; i < 4; i++) {
            int e = tid + i * 256;
            int row = e >> 3, cg = e & 7;
            float4 vb = *(const float4*)&W[(long)(n0 + row) * DMODEL + k0 + cg * 4];
            uint2 ub; ub.x = cvt_pk_bf16(vb.x, vb.y); ub.y = cvt_pk_bf16(vb.z, vb.w);
            *(uint2*)&Bt[row * 40 + cg * 4] = ub;
        }
        __syncthreads();
        bf16x8 af[4], bfr[4];
        #pragma unroll
        for (int f = 0; f < 4; f++) {
            af[f]  = *(const bf16x8*)&At[(64 * wr + 16 * f + l16) * 40 + 8 * lq];
            bfr[f] = *(const bf16x8*)&Bt[(64 * wc + 16 * f + l16) * 40 + 8 * lq];
        }
        #pragma unroll
        for (int i = 0; i < 4; i++)
            #pragma unroll
            for (int j = 0; j < 4; j++)
                acc[i][j] = __builtin_amdgcn_mfma_f32_16x16x32_bf16(af[i], bfr[j], acc[i][j], 0, 0, 0);
    }

    #pragma unroll
    for (int j = 0; j < 4; j++) {
        int n_g = n0 + 64 * wc + 16 * j + l16;
        float bias = Bv[n_g];
        #pragma unroll
        for (int i = 0; i < 4; i++) {
            #pragma unroll
            for (int r = 0; r < 4; r++) {
                int m_g = m0 + 64 * wr + 16 * i + 4 * lq + r;
                O[(long)m_g * DMODEL + n_g] = acc[i][j][r] + bias;
            }
        }
    }
}

// ---------------------------------------------------------------------------
extern "C" void kernel_launch(void* const* d_in, const int* in_sizes, int n_in,
                              void* d_out, int out_size, void* d_ws, size_t ws_size,
                              hipStream_t stream) {
    (void)in_sizes; (void)n_in; (void)out_size; (void)ws_size;
    const float* query = (const float*)d_in[0];
    const float* key_  = (const float*)d_in[1];
    const float* value = (const float*)d_in[2];
    const float* pos   = (const float*)d_in[3];
    const float* Wq = (const float*)d_in[4];  const float* bq = (const float*)d_in[5];
    const float* Wk = (const float*)d_in[6];  const float* bk = (const float*)d_in[7];
    const float* Wv = (const float*)d_in[8];  const float* bv = (const float*)d_in[9];
    const float* Wp = (const float*)d_in[10]; const float* bp = (const float*)d_in[11];
    const float* Wo = (const float*)d_in[12]; const float* bo = (const float*)d_in[13];
    float* out = (float*)d_out;

    const long NE = (long)TOKENS * DMODEL;   // 4,194,304 elements per tensor
    unsigned short* qb = (unsigned short*)d_ws;
    unsigned short* kb = qb + NE;
    unsigned short* vb = kb + NE;            // V^T layout [BH][64][S]
    unsigned short* pb = vb + NE;            // plain p table [BH][S][64]
    unsigned short* cx = pb + NE;            // total ws use: 5 * 8 MB = 40 MB

    proj_gemm<<<dim3(32, 8, 4), 256, 0, stream>>>(
        query, key_, value, pos, Wq, Wk, Wv, Wp, bq, bk, bv, bp, qb, kb, vb, pb);
    rel_attn<<<1024, 256, 0, stream>>>(qb, kb, vb, pb, cx);
    out_gemm<<<dim3(32, 8), 256, 0, stream>>>(cx, Wo, bo, out);
}